// Round 3
// baseline (1328.107 us; speedup 1.0000x reference)
//
#include <hip/hip_runtime.h>
#include <hip/hip_bf16.h>
#include <math.h>

#define MIN_POINTS 4

// ---- workspace layout (bytes) ----
#define WS_W0P   0         // 192 f32 SoA: [0..63]=wx, [64..127]=wy, [128..191]=wz
#define WS_B0P   768       // 64 f32
#define WS_W1P   1024      // 4096 f32 folded, row-major [co][k]
#define WS_B1P   17408     // 64 f32
#define WS_CNT   17920     // V ints (400000 B)
#define WS_P0    417920    // partial0 [1024][16] f64 (131072 B)
#define WS_P1    548992    // part1 [1024][128] f64 (1048576 B)
#define NPART    1024

// ---------------- K1: global stats of x (3-dim) + vertex counts ----------------
__global__ void k_stats0(const float4* __restrict__ d4, const int* __restrict__ idx,
                         double* __restrict__ partial0, int* __restrict__ cnt, int N){
  __shared__ double red[4][16];
  int tid = blockIdx.x*blockDim.x + threadIdx.x;
  int stride = gridDim.x*blockDim.x;
  double a[9] = {0,0,0,0,0,0,0,0,0};
  for (int i = tid; i < N; i += stride){
    float4 d = d4[i];
    double x0 = d.x, x1 = d.y, x2 = d.z;
    a[0] += x0; a[1] += x1; a[2] += x2;
    a[3] = fma(x0,x0,a[3]); a[4] = fma(x0,x1,a[4]); a[5] = fma(x0,x2,a[5]);
    a[6] = fma(x1,x1,a[6]); a[7] = fma(x1,x2,a[7]); a[8] = fma(x2,x2,a[8]);
    int v = idx[i]; if (v < 0) v = 0;
    atomicAdd(&cnt[v], 1);
  }
  int lane = threadIdx.x & 63, wid = threadIdx.x >> 6;
  #pragma unroll
  for (int j = 0; j < 9; j++){
    double v = a[j];
    for (int o = 32; o > 0; o >>= 1) v += __shfl_down(v, o, 64);
    if (lane == 0) red[wid][j] = v;
  }
  __syncthreads();
  if (threadIdx.x < 9){
    double s = red[0][threadIdx.x] + red[1][threadIdx.x]
             + red[2][threadIdx.x] + red[3][threadIdx.x];
    partial0[blockIdx.x*16 + threadIdx.x] = s;
  }
}

// ---------------- K2: reduce partials + fold layer-0 GN into W0' (SoA), b0' ----------------
__global__ void k_fold0(const double* __restrict__ partial0, const float* __restrict__ W0,
                        const float* __restrict__ g0, const float* __restrict__ bt0,
                        float* __restrict__ w0p, float* __restrict__ b0p, int N, int nparts){
  __shared__ double sred[16];
  int t = threadIdx.x, lane = t & 63, g = t >> 6;   // 1024 threads = 16 waves
  if (g < 9){
    double s = 0.0;
    for (int b = lane; b < nparts; b += 64) s += partial0[b*16 + g];
    for (int o = 32; o > 0; o >>= 1) s += __shfl_down(s, o, 64);
    if (lane == 0) sred[g] = s;
  }
  __syncthreads();
  if (t < 64){
    int c = t;
    double sx0 = sred[0], sx1 = sred[1], sx2 = sred[2];
    double G00 = sred[3], G01 = sred[4], G02 = sred[5], G11 = sred[6], G12 = sred[7], G22 = sred[8];
    double s[2], q[2];
    int chans[2] = { c, c ^ 1 };
    #pragma unroll
    for (int u = 0; u < 2; u++){
      int ch = chans[u];
      double w0 = W0[ch*3+0], w1 = W0[ch*3+1], w2 = W0[ch*3+2];
      s[u] = w0*sx0 + w1*sx1 + w2*sx2;
      q[u] = w0*w0*G00 + w1*w1*G11 + w2*w2*G22 + 2.0*(w0*w1*G01 + w0*w2*G02 + w1*w2*G12);
    }
    double inv  = 1.0 / (2.0 * (double)N);
    double mean = (s[0] + s[1]) * inv;
    double var  = (q[0] + q[1]) * inv - mean*mean;
    double aa   = (1.0 / sqrt(var + 1e-5)) * (double)g0[c];
    b0p[c] = (float)((double)bt0[c] - mean * aa);
    w0p[c]       = (float)((double)W0[c*3+0] * aa);   // SoA for scalar chunk loads
    w0p[64 + c]  = (float)((double)W0[c*3+1] * aa);
    w0p[128 + c] = (float)((double)W0[c*3+2] * aa);
  }
}

// ---------------- K3: per-channel sum/sumsq of raw y1 = h0 @ W1^T ----------------
// lane = row; weights wave-uniform via scalar loads; LDS transpose for f64 accum.
__global__ __launch_bounds__(256, 4)
void k_stats1(const float4* __restrict__ d4,
              const float* __restrict__ w0p, const float* __restrict__ b0p,
              const float* __restrict__ W1, double* __restrict__ part1,
              int N, int ntiles){
  __shared__ float buf[64][67];     // raw y1 [co][row]
  __shared__ double red[4][128];
  int lane = threadIdx.x & 63;
  int wid  = __builtin_amdgcn_readfirstlane((int)(threadIdx.x >> 6));
  int cbase = wid * 16;
  double s0 = 0.0, s1 = 0.0;
  for (int t = blockIdx.x; t < ntiles; t += gridDim.x){
    int rb = t * 64;
    int row = rb + lane;
    float4 d = (row < N) ? d4[row] : make_float4(0.f,0.f,0.f,0.f);
    float h0[64];
    #pragma unroll
    for (int c = 0; c < 64; c++){
      float t0 = b0p[c];
      t0 = fmaf(w0p[c],       d.x, t0);
      t0 = fmaf(w0p[64 + c],  d.y, t0);
      t0 = fmaf(w0p[128 + c], d.z, t0);
      h0[c] = fmaxf(t0, 0.f);
    }
    __syncthreads();              // prev accumulate reads of buf done
    #pragma unroll
    for (int u = 0; u < 16; u++){
      int co = cbase + u;
      const float* wr = &W1[co*64];     // wave-uniform -> s_load
      float a0 = 0.f, a1 = 0.f, a2 = 0.f, a3 = 0.f;
      #pragma unroll
      for (int k = 0; k < 64; k += 4){
        a0 = fmaf(wr[k+0], h0[k+0], a0);
        a1 = fmaf(wr[k+1], h0[k+1], a1);
        a2 = fmaf(wr[k+2], h0[k+2], a2);
        a3 = fmaf(wr[k+3], h0[k+3], a3);
      }
      buf[co][lane] = (a0 + a1) + (a2 + a3);   // raw, no bias/relu
    }
    __syncthreads();              // buf complete
    int rmax = min(64, N - rb);
    for (int rr = 0; rr < 16; rr++){
      int r = cbase + rr;         // this wave's 16 rows, lane = channel
      if (r < rmax){
        double y = (double)buf[lane][r];
        s0 += y;
        s1 = fma(y, y, s1);
      }
    }
  }
  __syncthreads();
  red[wid][lane]      = s0;
  red[wid][64 + lane] = s1;
  __syncthreads();
  if (threadIdx.x < 128){
    int t = threadIdx.x;
    part1[blockIdx.x*128 + t] = red[0][t] + red[1][t] + red[2][t] + red[3][t];
  }
}

// ---------------- K4: reduce partials + fold layer-1 GN into W1', b1' ----------------
__global__ void k_fold1(const double* __restrict__ part1, const float* __restrict__ W1,
                        const float* __restrict__ g1, const float* __restrict__ bt1,
                        float* __restrict__ w1p, float* __restrict__ b1p, int N, int nparts){
  __shared__ double sst[128];
  int t = threadIdx.x;          // 1024 threads
  int s = t >> 3, j = t & 7;    // 128 slots x 8 reducers
  double acc = 0.0;
  for (int b = j; b < nparts; b += 8) acc += part1[b*128 + s];
  acc += __shfl_down(acc, 4, 8);
  acc += __shfl_down(acc, 2, 8);
  acc += __shfl_down(acc, 1, 8);
  if (j == 0) sst[s] = acc;
  __syncthreads();
  if (t < 64){
    int c = t, p = c ^ 1;
    double inv  = 1.0 / (2.0 * (double)N);
    double mean = (sst[c] + sst[p]) * inv;
    double Ey2  = (sst[64+c] + sst[64+p]) * inv;
    double var  = Ey2 - mean*mean;
    double a    = (1.0 / sqrt(var + 1e-5)) * (double)g1[c];
    b1p[c] = (float)((double)bt1[c] - mean * a);
    for (int k = 0; k < 64; k++)
      w1p[c*64 + k] = (float)((double)W1[c*64 + k] * a);
  }
}

// ---------------- K5: fused main pass + packed segment atomicMax ----------------
// lane = row; per-wave 16 output channels; h1/y2 exchanged via LDS transpose.
__global__ __launch_bounds__(256, 4)
void k_main(const float4* __restrict__ d4, const int* __restrict__ idx,
            const float* __restrict__ w0p, const float* __restrict__ b0p,
            const float* __restrict__ w1p, const float* __restrict__ b1p,
            const float* __restrict__ W2,  const float* __restrict__ b2,
            unsigned long long* __restrict__ seg, int N, int ntiles){
  __shared__ float bufH[64][67];    // h1 [co][row]
  __shared__ float bufY[64][67];    // y2 [co][row]
  int lane = threadIdx.x & 63;
  int wid  = __builtin_amdgcn_readfirstlane((int)(threadIdx.x >> 6));
  int cbase = wid * 16;
  for (int t = blockIdx.x; t < ntiles; t += gridDim.x){
    int rb = t * 64;
    int row = rb + lane;
    float4 d = (row < N) ? d4[row] : make_float4(0.f,0.f,0.f,0.f);
    int myv = 0;
    if (row < N){ int v = idx[row]; myv = (v < 0) ? 0 : v; }
    // layer0: h0[64] per lane (redundant across the 4 waves; cheap)
    float h0[64];
    #pragma unroll
    for (int c = 0; c < 64; c++){
      float t0 = b0p[c];
      t0 = fmaf(w0p[c],       d.x, t0);
      t0 = fmaf(w0p[64 + c],  d.y, t0);
      t0 = fmaf(w0p[128 + c], d.z, t0);
      h0[c] = fmaxf(t0, 0.f);
    }
    __syncthreads();   // T: prev tile's bufY atomic reads + bufH reg-reads done
    // layer1 (folded): this wave's 16 channels, weights via scalar loads
    #pragma unroll
    for (int u = 0; u < 16; u++){
      int co = cbase + u;
      const float* wr = &w1p[co*64];
      float a0 = b1p[co], a1 = 0.f, a2 = 0.f, a3 = 0.f;
      #pragma unroll
      for (int k = 0; k < 64; k += 4){
        a0 = fmaf(wr[k+0], h0[k+0], a0);
        a1 = fmaf(wr[k+1], h0[k+1], a1);
        a2 = fmaf(wr[k+2], h0[k+2], a2);
        a3 = fmaf(wr[k+3], h0[k+3], a3);
      }
      bufH[co][lane] = fmaxf((a0 + a1) + (a2 + a3), 0.f);
    }
    __syncthreads();   // A: bufH complete
    float h1[64];
    #pragma unroll
    for (int k = 0; k < 64; k++) h1[k] = bufH[k][lane];
    // layer2 (raw W2 + b2)
    #pragma unroll
    for (int u = 0; u < 16; u++){
      int co = cbase + u;
      const float* wr = &W2[co*64];
      float a0 = b2[co], a1 = 0.f, a2 = 0.f, a3 = 0.f;
      #pragma unroll
      for (int k = 0; k < 64; k += 4){
        a0 = fmaf(wr[k+0], h1[k+0], a0);
        a1 = fmaf(wr[k+1], h1[k+1], a1);
        a2 = fmaf(wr[k+2], h1[k+2], a2);
        a3 = fmaf(wr[k+3], h1[k+3], a3);
      }
      bufY[co][lane] = fmaxf((a0 + a1) + (a2 + a3), 0.f);
    }
    __syncthreads();   // B: bufY complete
    // atomic phase: wave w handles rows [16w,16w+16); lane = channel -> coalesced
    int rmax = min(64, N - rb);
    for (int rr = 0; rr < 16; rr++){
      int r = cbase + rr;                    // uniform
      if (r < rmax){
        float y = bufY[lane][r];
        int v = __builtin_amdgcn_readlane(myv, r);   // uniform vertex of row r
        unsigned int bits = __float_as_uint(y) & 0x7fffffffu;  // -0 -> +0
        unsigned long long packed = ((unsigned long long)bits << 32)
            | (unsigned long long)(unsigned int)(~(unsigned int)(rb + r));
        atomicMax(&seg[(size_t)v*64 + lane], packed);
      }
    }
  }
}

// ---------------- K6: in-place unpack to final output ----------------
__global__ void k_out(const float4* __restrict__ d4, const int* __restrict__ cnt,
                      float* __restrict__ out, int N, int V){
  int lane = threadIdx.x & 63;
  int w = (int)((blockIdx.x*blockDim.x + threadIdx.x) >> 6);   // one wave per vertex
  if (w >= V) return;
  const unsigned long long* seg = (const unsigned long long*)out;
  unsigned long long p = seg[(size_t)w*64 + lane];
  int c = cnt[w];
  unsigned int bits = (unsigned int)(p >> 32);
  unsigned int rowu = ~(unsigned int)p;
  unsigned int nm1 = (unsigned int)(N - 1);
  if (rowu > nm1) rowu = nm1;
  float val  = __uint_as_float(bits);
  float bary = d4[rowu].w;
  bool few = (c < MIN_POINTS);
  float o0 = few ? 0.f : val;
  float o1 = few ? 0.f : bary;
  out[(size_t)w*128 + lane]      = o0;
  out[(size_t)w*128 + 64 + lane] = o1;
}

extern "C" void kernel_launch(void* const* d_in, const int* in_sizes, int n_in,
                              void* d_out, int out_size, void* d_ws, size_t ws_size,
                              hipStream_t stream) {
  const float4* d4  = (const float4*)d_in[0];
  const int*    idx = (const int*)d_in[1];
  const float*  W0  = (const float*)d_in[3];
  const float*  W1  = (const float*)d_in[4];
  const float*  W2  = (const float*)d_in[5];
  const float*  b2  = (const float*)d_in[6];
  const float*  g0  = (const float*)d_in[7];
  const float*  bt0 = (const float*)d_in[8];
  const float*  g1  = (const float*)d_in[9];
  const float*  bt1 = (const float*)d_in[10];

  int N = in_sizes[0] / 4;
  int V = out_size / 128;
  int ntiles = (N + 63) / 64;

  char* ws = (char*)d_ws;
  float*  w0p = (float*)(ws + WS_W0P);
  float*  b0p = (float*)(ws + WS_B0P);
  float*  w1p = (float*)(ws + WS_W1P);
  float*  b1p = (float*)(ws + WS_B1P);
  int*    cnt = (int*)(ws + WS_CNT);
  double* p0  = (double*)(ws + WS_P0);
  double* p1  = (double*)(ws + WS_P1);

  hipMemsetAsync(cnt, 0, (size_t)V * sizeof(int), stream);
  hipMemsetAsync(d_out, 0, (size_t)out_size * sizeof(float), stream);

  k_stats0<<<NPART, 256, 0, stream>>>(d4, idx, p0, cnt, N);
  k_fold0 <<<1, 1024, 0, stream>>>(p0, W0, g0, bt0, w0p, b0p, N, NPART);
  k_stats1<<<NPART, 256, 0, stream>>>(d4, w0p, b0p, W1, p1, N, ntiles);
  k_fold1 <<<1, 1024, 0, stream>>>(p1, W1, g1, bt1, w1p, b1p, N, NPART);
  k_main  <<<NPART, 256, 0, stream>>>(d4, idx, w0p, b0p, w1p, b1p, W2, b2,
                                      (unsigned long long*)d_out, N, ntiles);
  k_out   <<<(V + 3) / 4, 256, 0, stream>>>(d4, cnt, (float*)d_out, N, V);
}